// Round 3
// baseline (12432.803 us; speedup 1.0000x reference)
//
#include <hip/hip_runtime.h>
#include <math.h>

// Problem constants
#define B_    32
#define T_    1000
#define E_    512
#define D_    1024
#define A_    512
#define C_    10
#define F_    100
#define ODIM_ 5000
#define OLEN_ 101
#define SOS_  4998

// ---- workspace layout (float offsets) ----
#define OFF_PRE   0u
#define N_PRE     (32u*1000u*512u)          // 16,384,000
#define OFF_DEC   (OFF_PRE + N_PRE)         // [B][A]
#define N_DEC     (32u*512u)
#define OFF_CONV  (OFF_DEC + N_DEC)         // (reused: OFF_SUM lives here now)
#define N_CONVB   (32u*10u*1000u)
#define OFF_SUM   OFF_CONV                  // [B] softmax denominators
#define OFF_EB    (OFF_CONV + N_CONVB)      // [B][T] p = exp(2e)
#define N_EB      (32u*1000u)
#define OFF_AW    (OFF_EB + N_EB)           // [B][T] attention weights
#define OFF_CTX   (OFF_AW + N_EB)           // [B][E]
#define N_CTX     (32u*512u)
#define OFF_GP    (OFF_CTX + N_CTX)         // [10][B][4096] gate partials
#define N_GP      (10u*32u*4096u)
#define OFF_Z     (OFF_GP + N_GP)           // [B][D]
#define N_Z       (32u*1024u)
#define OFF_C     (OFF_Z + N_Z)             // [B][D]
#define OFF_ZALL  (OFF_C + N_Z)             // [101][B][D]

// ---- fast transcendentals (hw v_exp_f32 / v_rcp_f32) ----
__device__ __forceinline__ float fast_tanh(float x) {
    float cx = fminf(8.f, fmaxf(-8.f, x));
    float e = __expf(2.f * cx);
    return (e - 1.f) * __builtin_amdgcn_rcpf(e + 1.f);
}
__device__ __forceinline__ float fast_sigmoid(float x) {
    float cx = fminf(30.f, fmaxf(-30.f, x));
    return __builtin_amdgcn_rcpf(1.f + __expf(-cx));
}

// ---------------- init: z=0, c=0, aw=1/T, sums=0 ----------------
__global__ __launch_bounds__(256) void k_init(float* ws) {
    int i = blockIdx.x * 256 + threadIdx.x;
    if (i < (int)N_Z) { ws[OFF_Z + i] = 0.f; ws[OFF_C + i] = 0.f; }
    if (i < (int)N_EB) ws[OFF_AW + i] = 1.0f / (float)T_;
    if (i < 32) ws[OFF_SUM + i] = 0.f;
}

// ---------------- pre = hpad @ w_enc^T + b_enc ----------------
__global__ __launch_bounds__(256) void k_pre(const float* __restrict__ hp,
                                             const float* __restrict__ we,
                                             const float* __restrict__ be,
                                             float* __restrict__ pre) {
    __shared__ float As[64][68];
    __shared__ float Bs[64][68];
    int m0 = blockIdx.y * 64, n0 = blockIdx.x * 64;
    int tid = threadIdx.x;
    int tr = tid >> 4, tc = tid & 15;
    float acc[4][4] = {};
    for (int k0 = 0; k0 < 512; k0 += 64) {
        for (int i = tid; i < 1024; i += 256) {
            int m = i >> 4, kq = (i & 15) << 2;
            float4 v = *(const float4*)&hp[(size_t)(m0 + m) * 512 + k0 + kq];
            As[kq + 0][m] = v.x; As[kq + 1][m] = v.y; As[kq + 2][m] = v.z; As[kq + 3][m] = v.w;
            float4 w = *(const float4*)&we[(size_t)(n0 + m) * 512 + k0 + kq];
            Bs[kq + 0][m] = w.x; Bs[kq + 1][m] = w.y; Bs[kq + 2][m] = w.z; Bs[kq + 3][m] = w.w;
        }
        __syncthreads();
        #pragma unroll 16
        for (int kk = 0; kk < 64; ++kk) {
            float4 av = *(const float4*)&As[kk][tr << 2];
            float4 bv = *(const float4*)&Bs[kk][tc << 2];
            float a[4] = {av.x, av.y, av.z, av.w};
            float b[4] = {bv.x, bv.y, bv.z, bv.w};
            #pragma unroll
            for (int i = 0; i < 4; i++)
                #pragma unroll
                for (int j = 0; j < 4; j++) acc[i][j] += a[i] * b[j];
        }
        __syncthreads();
    }
    #pragma unroll
    for (int i = 0; i < 4; i++) {
        int m = m0 + (tr << 2) + i;
        int n = n0 + (tc << 2);
        float4 o;
        o.x = acc[i][0] + be[n + 0];
        o.y = acc[i][1] + be[n + 1];
        o.z = acc[i][2] + be[n + 2];
        o.w = acc[i][3] + be[n + 3];
        *(float4*)&pre[(size_t)m * 512 + n] = o;
    }
}

// ---------------- per-step dec = z @ w_dec^T ----------------
// wave per a (512 waves = 128 blocks x 4); each wave loops all 32 b.
// w_dec read exactly once (2 MB); z stays hot in L1/L2.
__global__ __launch_bounds__(256) void k_dec(const float* __restrict__ wdec, float* ws) {
    int a = blockIdx.x * 4 + (threadIdx.x >> 6);
    int lane = threadIdx.x & 63;
    const float4* wr = (const float4*)(wdec + (size_t)a * 1024);
    float4 w4[4];
    #pragma unroll
    for (int j = 0; j < 4; j++) w4[j] = wr[j * 64 + lane];
    const float4* z4 = (const float4*)(ws + OFF_Z);
    for (int b = 0; b < 32; ++b) {
        float acc = 0.f;
        #pragma unroll
        for (int j = 0; j < 4; j++) {
            float4 z = z4[b * 256 + j * 64 + lane];
            acc += w4[j].x * z.x + w4[j].y * z.y + w4[j].z * z.z + w4[j].w * z.w;
        }
        #pragma unroll
        for (int off = 32; off > 0; off >>= 1) acc += __shfl_xor(acc, off, 64);
        if (lane == 0) ws[OFF_DEC + b * 512 + a] = acc;
    }
}

// ---------------- per-step fused conv + energy + exp + partial softmax sum ----
// grid = 32 b x 8 t-chunks (125 t each); block 512 (8 waves).
// Phase A: conv [10][125] into LDS from aw window. Phase B: wave per ~16 t's,
// lanes over a (8 a's/lane), writes p=exp(2e) and accumulates sum[b].
__global__ __launch_bounds__(512) void k_attn(const float* __restrict__ watt,
                                              const float* __restrict__ gvec,
                                              const float* __restrict__ bg,
                                              const float* __restrict__ wconv,
                                              float* ws) {
    __shared__ float aw_lds[328];
    __shared__ float conv_lds[10][126];
    __shared__ float psum;
    int b  = blockIdx.x >> 3;
    int tc = blockIdx.x & 7;
    int t0 = tc * 125;
    int tid = threadIdx.x;
    if (tid < 64) ws[OFF_CTX + b * 512 + tc * 64 + tid] = 0.f;  // zero ctx for k_ctx
    if (tid == 0) psum = 0.f;
    if (tid < 328) {
        int tg = t0 - 100 + tid;
        aw_lds[tid] = (tg >= 0 && tg < 1000) ? ws[OFF_AW + b * 1000 + tg] : 0.f;
    }
    __syncthreads();
    for (int i = tid; i < 1250; i += 512) {
        int c = i / 125, tl = i - c * 125;
        const float* wc = wconv + c * 201;
        float acc = 0.f;
        #pragma unroll 4
        for (int j = 0; j < 201; ++j) acc += aw_lds[tl + j] * wc[j];
        conv_lds[c][tl] = acc;
    }
    int lane = tid & 63, w = tid >> 6;
    int a0 = lane * 4, a1 = 256 + lane * 4;
    float wr[8][10];
    #pragma unroll
    for (int i = 0; i < 4; i++)
        #pragma unroll
        for (int c = 0; c < 10; c++) {
            wr[i][c]     = watt[(a0 + i) * 10 + c];
            wr[4 + i][c] = watt[(a1 + i) * 10 + c];
        }
    float4 d0 = *(const float4*)&ws[OFF_DEC + b * 512 + a0];
    float4 d1 = *(const float4*)&ws[OFF_DEC + b * 512 + a1];
    float4 g0 = *(const float4*)&gvec[a0];
    float4 g1 = *(const float4*)&gvec[a1];
    float dc[8] = {d0.x, d0.y, d0.z, d0.w, d1.x, d1.y, d1.z, d1.w};
    float gv[8] = {g0.x, g0.y, g0.z, g0.w, g1.x, g1.y, g1.z, g1.w};
    float bgv = bg[0];
    __syncthreads();
    float lsum = 0.f;
    int tlo = w * 16, thi = tlo + 16; if (thi > 125) thi = 125;
    for (int tl = tlo; tl < thi; ++tl) {
        int t = t0 + tl;
        const float* pr = ws + OFF_PRE + (size_t)(b * 1000 + t) * 512;
        float4 p0 = *(const float4*)&pr[a0];
        float4 p1 = *(const float4*)&pr[a1];
        float cv[10];
        #pragma unroll
        for (int c = 0; c < 10; c++) cv[c] = conv_lds[c][tl];
        float pa[8] = {p0.x, p0.y, p0.z, p0.w, p1.x, p1.y, p1.z, p1.w};
        float acc = 0.f;
        #pragma unroll
        for (int i = 0; i < 8; i++) {
            float s = pa[i] + dc[i];
            #pragma unroll
            for (int c = 0; c < 10; c++) s += cv[c] * wr[i][c];
            acc += gv[i] * fast_tanh(s);
        }
        #pragma unroll
        for (int off = 32; off > 0; off >>= 1) acc += __shfl_xor(acc, off, 64);
        if (lane == 0) {
            float p = __expf(2.f * (acc + bgv));
            ws[OFF_EB + b * 1000 + t] = p;
            lsum += p;
        }
    }
    if (lane == 0) atomicAdd(&psum, lsum);
    __syncthreads();
    if (tid == 0) atomicAdd(&ws[OFF_SUM + b], psum);
}

// ---------------- per-step ctx (+ normalize p -> aw) ----------------
// grid = 32 b x 32 tsplit; 128 threads (float4 over e)
__global__ __launch_bounds__(128) void k_ctx(const float* __restrict__ hp, float* ws) {
    int b = blockIdx.x >> 5, ts = blockIdx.x & 31;
    int t0 = ts * 32;
    int t1 = t0 + 32; if (t1 > 1000) t1 = 1000;
    int tid = threadIdx.x;
    float inv = __builtin_amdgcn_rcpf(ws[OFF_SUM + b]);
    const float* pb = ws + OFF_EB + b * 1000;
    if (tid < t1 - t0) ws[OFF_AW + b * 1000 + t0 + tid] = pb[t0 + tid] * inv;
    const float4* hp4 = (const float4*)hp;
    float4 acc = make_float4(0.f, 0.f, 0.f, 0.f);
    for (int t = t0; t < t1; ++t) {
        float w = pb[t] * inv;
        float4 h = hp4[(size_t)(b * 1000 + t) * 128 + tid];
        acc.x += w * h.x; acc.y += w * h.y; acc.z += w * h.z; acc.w += w * h.w;
    }
    float* cx = ws + OFF_CTX + b * 512 + tid * 4;
    atomicAdd(cx + 0, acc.x); atomicAdd(cx + 1, acc.y);
    atomicAdd(cx + 2, acc.z); atomicAdd(cx + 3, acc.w);
}

// ---------------- per-step gate partials (tiled GEMM, LDS-staged) ----------------
__global__ __launch_bounds__(128) void k_gates(const float* __restrict__ wih,
                                               const float* __restrict__ whh,
                                               const float* __restrict__ embed,
                                               const int* __restrict__ ys,
                                               float* ws, int step) {
    __shared__ float wlds[32][68];
    __shared__ float xs[32][36];
    int nt = blockIdx.x & 63;
    int ks = blockIdx.x >> 6;          // 0..9
    int n0 = nt * 64;
    int tid = threadIdx.x;
    int nq = tid & 15, bq = tid >> 4;
    float acc[4][4] = {};
    for (int kc = 0; kc < 8; ++kc) {
        int k0 = ks * 256 + kc * 32;
        {
            int r = tid >> 1, h = tid & 1;
            int gn = n0 + r;
            const float* wrow = (k0 < 1536)
                ? (wih + (size_t)gn * 1536 + k0 + h * 16)
                : (whh + (size_t)gn * 1024 + (k0 - 1536) + h * 16);
            #pragma unroll
            for (int j = 0; j < 4; ++j) {
                float4 v = *(const float4*)&wrow[j * 4];
                int kb = h * 16 + j * 4;
                wlds[kb + 0][r] = v.x; wlds[kb + 1][r] = v.y;
                wlds[kb + 2][r] = v.z; wlds[kb + 3][r] = v.w;
            }
        }
        {
            int b = tid >> 2, q = tid & 3;
            int tok = (step == 0) ? SOS_ : ys[b * 100 + step - 1];
            #pragma unroll
            for (int j = 0; j < 2; ++j) {
                int kk = k0 + q * 8 + j * 4;
                float4 v;
                if (kk < 1024)       v = *(const float4*)&embed[(size_t)tok * 1024 + kk];
                else if (kk < 1536)  v = *(const float4*)&ws[OFF_CTX + b * 512 + kk - 1024];
                else                 v = *(const float4*)&ws[OFF_Z + b * 1024 + kk - 1536];
                int kb = q * 8 + j * 4;
                xs[kb + 0][b] = v.x; xs[kb + 1][b] = v.y;
                xs[kb + 2][b] = v.z; xs[kb + 3][b] = v.w;
            }
        }
        __syncthreads();
        #pragma unroll 8
        for (int kk = 0; kk < 32; ++kk) {
            float4 wv = *(const float4*)&wlds[kk][nq * 4];
            float4 xv = *(const float4*)&xs[kk][bq * 4];
            float wa[4] = {wv.x, wv.y, wv.z, wv.w};
            float xa[4] = {xv.x, xv.y, xv.z, xv.w};
            #pragma unroll
            for (int i = 0; i < 4; i++)
                #pragma unroll
                for (int j = 0; j < 4; j++) acc[i][j] += wa[i] * xa[j];
        }
        __syncthreads();
    }
    float* gp = ws + OFF_GP + (size_t)(ks * 32 + bq * 4) * 4096 + n0 + nq * 4;
    #pragma unroll
    for (int j = 0; j < 4; j++)
        #pragma unroll
        for (int i = 0; i < 4; i++)
            gp[(size_t)j * 4096 + i] = acc[i][j];
}

// ---------------- per-step LSTM elementwise (+ zero sums for next step) -------
__global__ __launch_bounds__(256) void k_lstm(const float* __restrict__ bih,
                                              const float* __restrict__ bhh,
                                              float* ws, int step) {
    if (blockIdx.x == 0 && threadIdx.x < 32) ws[OFF_SUM + threadIdx.x] = 0.f;
    int id = blockIdx.x * 256 + threadIdx.x;
    int b = id >> 10, d = id & 1023;
    float gi = bih[d] + bhh[d];
    float gf = bih[1024 + d] + bhh[1024 + d];
    float gg = bih[2048 + d] + bhh[2048 + d];
    float go = bih[3072 + d] + bhh[3072 + d];
    const float* gp = ws + OFF_GP;
    #pragma unroll
    for (int kc = 0; kc < 10; kc++) {
        const float* r = gp + (size_t)(kc * 32 + b) * 4096;
        gi += r[d];
        gf += r[1024 + d];
        gg += r[2048 + d];
        go += r[3072 + d];
    }
    float c_old = ws[OFF_C + id];
    float si = fast_sigmoid(gi);
    float sf = fast_sigmoid(gf);
    float so = fast_sigmoid(go);
    float cn = sf * c_old + si * fast_tanh(gg);
    float h = so * fast_tanh(cn);
    ws[OFF_C + id] = cn;
    ws[OFF_Z + id] = h;
    ws[OFF_ZALL + ((size_t)step * 32 + b) * 1024 + d] = h;
}

// ---------------- final: out[b,o,v] = zall[o,b,:] @ w_out[v,:] + b_out[v] -----
__global__ __launch_bounds__(256) void k_out(const float* __restrict__ zall,
                                             const float* __restrict__ wo,
                                             const float* __restrict__ bo,
                                             float* __restrict__ out) {
    __shared__ float As[64][68];
    __shared__ float Bs[64][68];
    int m0 = blockIdx.y * 64, n0 = blockIdx.x * 64;
    int tid = threadIdx.x;
    int tr = tid >> 4, tc = tid & 15;
    float acc[4][4] = {};
    for (int k0 = 0; k0 < 1024; k0 += 64) {
        for (int i = tid; i < 1024; i += 256) {
            int m = i >> 4, kq = (i & 15) << 2;
            int gm = m0 + m;
            float4 v = (gm < 3232) ? *(const float4*)&zall[(size_t)gm * 1024 + k0 + kq]
                                   : make_float4(0.f, 0.f, 0.f, 0.f);
            As[kq + 0][m] = v.x; As[kq + 1][m] = v.y; As[kq + 2][m] = v.z; As[kq + 3][m] = v.w;
            int gn = n0 + m;
            float4 w = (gn < 5000) ? *(const float4*)&wo[(size_t)gn * 1024 + k0 + kq]
                                   : make_float4(0.f, 0.f, 0.f, 0.f);
            Bs[kq + 0][m] = w.x; Bs[kq + 1][m] = w.y; Bs[kq + 2][m] = w.z; Bs[kq + 3][m] = w.w;
        }
        __syncthreads();
        #pragma unroll 16
        for (int kk = 0; kk < 64; ++kk) {
            float4 av = *(const float4*)&As[kk][tr << 2];
            float4 bv = *(const float4*)&Bs[kk][tc << 2];
            float a[4] = {av.x, av.y, av.z, av.w};
            float b[4] = {bv.x, bv.y, bv.z, bv.w};
            #pragma unroll
            for (int i = 0; i < 4; i++)
                #pragma unroll
                for (int j = 0; j < 4; j++) acc[i][j] += a[i] * b[j];
        }
        __syncthreads();
    }
    #pragma unroll
    for (int i = 0; i < 4; i++) {
        int m = m0 + (tr << 2) + i;
        if (m >= 3232) continue;
        int b = m & 31, o = m >> 5;
        #pragma unroll
        for (int j = 0; j < 4; j++) {
            int v = n0 + (tc << 2) + j;
            if (v < 5000)
                out[((size_t)b * 101 + o) * 5000 + v] = acc[i][j] + bo[v];
        }
    }
}

extern "C" void kernel_launch(void* const* d_in, const int* in_sizes, int n_in,
                              void* d_out, int out_size, void* d_ws, size_t ws_size,
                              hipStream_t stream) {
    const float* hpad   = (const float*)d_in[0];
    const int*   ys     = (const int*)d_in[1];
    const float* w_enc  = (const float*)d_in[2];
    const float* b_enc  = (const float*)d_in[3];
    const float* w_dec  = (const float*)d_in[4];
    const float* w_att  = (const float*)d_in[5];
    const float* w_conv = (const float*)d_in[6];
    const float* w_gvec = (const float*)d_in[7];
    const float* b_gvec = (const float*)d_in[8];
    const float* embed  = (const float*)d_in[9];
    const float* w_ih   = (const float*)d_in[10];
    const float* w_hh   = (const float*)d_in[11];
    const float* b_ih   = (const float*)d_in[12];
    const float* b_hh   = (const float*)d_in[13];
    const float* w_out  = (const float*)d_in[14];
    const float* b_out  = (const float*)d_in[15];
    float* ws  = (float*)d_ws;
    float* out = (float*)d_out;

    k_init<<<128, 256, 0, stream>>>(ws);
    k_pre<<<dim3(8, 500), 256, 0, stream>>>(hpad, w_enc, b_enc, ws + OFF_PRE);

    for (int step = 0; step < OLEN_; ++step) {
        k_dec<<<128, 256, 0, stream>>>(w_dec, ws);
        k_attn<<<256, 512, 0, stream>>>(w_att, w_gvec, b_gvec, w_conv, ws);
        k_ctx<<<1024, 128, 0, stream>>>(hpad, ws);
        k_gates<<<640, 128, 0, stream>>>(w_ih, w_hh, embed, ys, ws, step);
        k_lstm<<<128, 256, 0, stream>>>(b_ih, b_hh, ws, step);
    }

    k_out<<<dim3(79, 51), 256, 0, stream>>>(ws + OFF_ZALL, w_out, b_out, out);
}